// Round 1
// baseline (128.510 us; speedup 1.0000x reference)
//
#include <hip/hip_runtime.h>
#include <hip/hip_bf16.h>

// SimpleGATLayer fused kernel set for MI355X (gfx950).
// B=8, N=2048, F=U=128 (hard-coded from reference setup).
//
//  k_wt  : W(f,u) f32 -> WT(u,f) bf16            (tiny)
//  k_h   : H = X@W via MFMA; writes HT(b,u,n) bf16, s(b,n), t(b,n) f32
//  k_attn: flash-style masked softmax(leaky(s_i+t_j)+mask) @ H, relu, f32 out

#define NEG_INF -1.0e9f

typedef __bf16 bf16x8 __attribute__((ext_vector_type(8)));
typedef unsigned short ushort8 __attribute__((ext_vector_type(8)));
typedef float f32x4 __attribute__((ext_vector_type(4)));

__device__ __forceinline__ unsigned short f2b(float x) {
    // f32 -> bf16 round-to-nearest-even (values here are finite, no NaN care)
    unsigned u = __builtin_bit_cast(unsigned, x);
    u += 0x7fffu + ((u >> 16) & 1u);
    return (unsigned short)(u >> 16);
}

// ---------------- K0: W transpose+convert ----------------
__global__ __launch_bounds__(256) void k_wt(const float* __restrict__ W,
                                            unsigned short* __restrict__ WT) {
    int tid = blockIdx.x * 256 + threadIdx.x;   // 16384 elements
    int u = tid >> 7, f = tid & 127;
    WT[tid] = f2b(W[f * 128 + u]);              // WT[u][f] = W[f][u]
}

// ---------------- K1: H = X@W, plus s,t and HT ----------------
// grid = 256 blocks x 256 thr; each wave computes 16 rows x 128 u.
__global__ __launch_bounds__(256) void k_h(const float* __restrict__ X,
                                           const unsigned short* __restrict__ WT,
                                           const float* __restrict__ a,
                                           unsigned short* __restrict__ HT,
                                           float* __restrict__ sbuf,
                                           float* __restrict__ tbuf) {
    const int tid  = threadIdx.x;
    const int w    = tid >> 6;
    const int lane = tid & 63;
    const int r    = lane & 15;     // MFMA row/col index
    const int cg   = lane >> 4;     // k-group 0..3
    const int row0 = blockIdx.x * 64 + w * 16;  // flattened (b*2048+n) row of wave
    const int b    = row0 >> 11;
    const int n0   = row0 & 2047;
    const int arow = row0 + r;

    f32x4 acc[8] = {};

#pragma unroll
    for (int k0 = 0; k0 < 128; k0 += 32) {
        // A-fragment: X[arow][k0 + cg*8 + jj]  (f32 -> bf16)
        const float* xp = X + (size_t)arow * 128 + k0 + cg * 8;
        ushort8 xa;
#pragma unroll
        for (int j = 0; j < 8; j++) xa[j] = f2b(xp[j]);
        bf16x8 av = __builtin_bit_cast(bf16x8, xa);
#pragma unroll
        for (int ut = 0; ut < 8; ut++) {
            // B-fragment: W[k][u] = WT[ut*16+r][k0+cg*8 .. +7]  (16B contiguous)
            ushort8 wb = *(const ushort8*)(WT + (size_t)(ut * 16 + r) * 128 + k0 + cg * 8);
            acc[ut] = __builtin_amdgcn_mfma_f32_16x16x32_bf16(
                av, __builtin_bit_cast(bf16x8, wb), acc[ut], 0, 0, 0);
        }
    }

    // D layout: lane holds H[row0 + cg*4 + reg][ut*16 + r]
    float sp[4] = {0.f, 0.f, 0.f, 0.f};
    float tp[4] = {0.f, 0.f, 0.f, 0.f};
#pragma unroll
    for (int ut = 0; ut < 8; ut++) {
        int u = ut * 16 + r;
        float as = a[u];
        float ad = a[128 + u];
#pragma unroll
        for (int reg = 0; reg < 4; reg++) {
            float h = acc[ut][reg];
            int nrow = n0 + cg * 4 + reg;
            HT[((size_t)b * 128 + u) * 2048 + nrow] = f2b(h);
            sp[reg] += h * as;
            tp[reg] += h * ad;
        }
    }
    // reduce partial dot-products across the 16 column-lanes (bits 0..3)
#pragma unroll
    for (int msk = 1; msk < 16; msk <<= 1) {
#pragma unroll
        for (int reg = 0; reg < 4; reg++) {
            sp[reg] += __shfl_xor(sp[reg], msk);
            tp[reg] += __shfl_xor(tp[reg], msk);
        }
    }
    if (r == 0) {
#pragma unroll
        for (int reg = 0; reg < 4; reg++) {
            int row = row0 + cg * 4 + reg;
            sbuf[row] = sp[reg];
            tbuf[row] = tp[reg];
        }
    }
}

// ---------------- K2: fused masked-softmax attention @ H ----------------
// grid = (N/64, 2, B); block = 256 (4 waves).
// Wave handles 16 i-rows x 64 u-cols, iterating j in tiles of 32 with online softmax.
__global__ __launch_bounds__(256) void k_attn(const int* __restrict__ A,
                                              const unsigned short* __restrict__ HT,
                                              const float* __restrict__ sbuf,
                                              const float* __restrict__ tbuf,
                                              float* __restrict__ out) {
    const int tid  = threadIdx.x;
    const int w    = tid >> 6;
    const int lane = tid & 63;
    const int r    = lane & 15;
    const int cg   = lane >> 4;
    const int b    = blockIdx.z;
    const int u0   = blockIdx.y * 64;
    const int i0   = blockIdx.x * 64 + w * 16;   // batch-local i base of wave
    const int srow = i0 + r;                     // P row owned by this lane

    const float s_r = sbuf[b * 2048 + srow];
    const int* Arow = A + ((size_t)b * 2048 + srow) * 2048;
    const float* tb = tbuf + (size_t)b * 2048;
    const unsigned short* Hb = HT + (size_t)b * 128 * 2048;

    f32x4 acc[4] = {};
    float m = NEG_INF;
    float den = 0.f;

    for (int j0 = 0; j0 < 2048; j0 += 32) {
        const int jb = j0 + cg * 8;
        int4 a0 = *(const int4*)(Arow + jb);
        int4 a1 = *(const int4*)(Arow + jb + 4);
        float4 t0 = *(const float4*)(tb + jb);
        float4 t1 = *(const float4*)(tb + jb + 4);
        int   ai[8] = {a0.x, a0.y, a0.z, a0.w, a1.x, a1.y, a1.z, a1.w};
        float tv[8] = {t0.x, t0.y, t0.z, t0.w, t1.x, t1.y, t1.z, t1.w};

        float ev[8];
        float mloc = NEG_INF;
#pragma unroll
        for (int jj = 0; jj < 8; jj++) {
            float x = s_r + tv[jj];
            float e = x > 0.f ? x : 0.2f * x;        // leaky_relu
            e = ai[jj] > 0 ? e : NEG_INF;            // mask
            ev[jj] = e;
            mloc = fmaxf(mloc, e);
        }
        // row max across the 4 k-groups holding this row
        mloc = fmaxf(mloc, __shfl_xor(mloc, 16));
        mloc = fmaxf(mloc, __shfl_xor(mloc, 32));
        float mn  = fmaxf(m, mloc);
        float fac = __expf(m - mn);

        float psum = 0.f;
        ushort8 pb;
#pragma unroll
        for (int jj = 0; jj < 8; jj++) {
            float p = ai[jj] > 0 ? __expf(ev[jj] - mn) : 0.f;
            psum += p;
            pb[jj] = f2b(p);
        }
        den = den * fac + psum;
        m = mn;

        // rescale accumulators (acc rows are cg*4+reg; fetch their factors)
        if (__any(fac < 1.f)) {
            float f0 = __shfl(fac, cg * 4 + 0);
            float f1 = __shfl(fac, cg * 4 + 1);
            float f2 = __shfl(fac, cg * 4 + 2);
            float f3 = __shfl(fac, cg * 4 + 3);
#pragma unroll
            for (int ut = 0; ut < 4; ut++) {
                acc[ut][0] *= f0;
                acc[ut][1] *= f1;
                acc[ut][2] *= f2;
                acc[ut][3] *= f3;
            }
        }

        bf16x8 pa = __builtin_bit_cast(bf16x8, pb);
#pragma unroll
        for (int ut = 0; ut < 4; ut++) {
            // B-fragment: H[j][u] = HT[u0+ut*16+r][jb .. jb+7] (16B contiguous)
            ushort8 hb = *(const ushort8*)(Hb + (size_t)(u0 + ut * 16 + r) * 2048 + jb);
            acc[ut] = __builtin_amdgcn_mfma_f32_16x16x32_bf16(
                pa, __builtin_bit_cast(bf16x8, hb), acc[ut], 0, 0, 0);
        }
    }

    // total denominator per row: sum the 4 k-group partials (same running m)
    den += __shfl_xor(den, 16);
    den += __shfl_xor(den, 32);
    float dr[4];
#pragma unroll
    for (int reg = 0; reg < 4; reg++) dr[reg] = __shfl(den, cg * 4 + reg);

#pragma unroll
    for (int ut = 0; ut < 4; ut++) {
#pragma unroll
        for (int reg = 0; reg < 4; reg++) {
            float o = acc[ut][reg] / dr[reg];
            o = fmaxf(o, 0.f);
            out[((size_t)b * 2048 + i0 + cg * 4 + reg) * 128 + u0 + ut * 16 + r] = o;
        }
    }
}

extern "C" void kernel_launch(void* const* d_in, const int* in_sizes, int n_in,
                              void* d_out, int out_size, void* d_ws, size_t ws_size,
                              hipStream_t stream) {
    const float* X = (const float*)d_in[0];   // (8,2048,128) f32
    const int*   A = (const int*)d_in[1];     // (8,2048,2048) i32
    const float* W = (const float*)d_in[2];   // (128,128) f32
    const float* a = (const float*)d_in[3];   // (256,1) f32
    float* out = (float*)d_out;               // (8,2048,128) f32

    char* ws = (char*)d_ws;
    unsigned short* WT  = (unsigned short*)(ws);                  // 32 KB
    float*          sb  = (float*)(ws + 32768);                   // 64 KB
    float*          tb  = (float*)(ws + 32768 + 65536);           // 64 KB
    unsigned short* HT  = (unsigned short*)(ws + 32768 + 131072); // 4 MB

    k_wt<<<dim3(64), dim3(256), 0, stream>>>(W, WT);
    k_h<<<dim3(256), dim3(256), 0, stream>>>(X, WT, a, HT, sb, tb);
    k_attn<<<dim3(32, 2, 8), dim3(256), 0, stream>>>(A, HT, sb, tb, out);
}

// Round 2
// 94.919 us; speedup vs baseline: 1.3539x; 1.3539x over previous
//
#include <hip/hip_runtime.h>
#include <hip/hip_bf16.h>

// SimpleGATLayer fused kernel set for MI355X (gfx950).
// B=8, N=2048, F=U=128 (hard-coded from reference setup).
//
//  k_wt  : W(f,u) f32 -> WT(u,f) bf16            (tiny)
//  k_h   : H = X@W via MFMA; writes HT(b,u,n) bf16, s(b,n), t(b,n) f32
//  k_attn: flash-style masked softmax(leaky(s_i+t_j)+mask) @ H, relu, f32 out
//          Round 2: j-split across the 4 waves of a block (flash-decoding
//          style) + LDS combine. 1024 blocks -> 4 blocks/CU, u=128 in one
//          pass (A read once), manual A/t prefetch.

#define NEG_INF -1.0e9f

typedef __bf16 bf16x8 __attribute__((ext_vector_type(8)));
typedef unsigned short ushort8 __attribute__((ext_vector_type(8)));
typedef float f32x4 __attribute__((ext_vector_type(4)));

__device__ __forceinline__ unsigned short f2b(float x) {
    // f32 -> bf16 round-to-nearest-even (values here are finite, no NaN care)
    unsigned u = __builtin_bit_cast(unsigned, x);
    u += 0x7fffu + ((u >> 16) & 1u);
    return (unsigned short)(u >> 16);
}

// ---------------- K0: W transpose+convert ----------------
__global__ __launch_bounds__(256) void k_wt(const float* __restrict__ W,
                                            unsigned short* __restrict__ WT) {
    int tid = blockIdx.x * 256 + threadIdx.x;   // 16384 elements
    int u = tid >> 7, f = tid & 127;
    WT[tid] = f2b(W[f * 128 + u]);              // WT[u][f] = W[f][u]
}

// ---------------- K1: H = X@W, plus s,t and HT ----------------
// grid = 256 blocks x 256 thr; each wave computes 16 rows x 128 u.
__global__ __launch_bounds__(256) void k_h(const float* __restrict__ X,
                                           const unsigned short* __restrict__ WT,
                                           const float* __restrict__ a,
                                           unsigned short* __restrict__ HT,
                                           float* __restrict__ sbuf,
                                           float* __restrict__ tbuf) {
    const int tid  = threadIdx.x;
    const int w    = tid >> 6;
    const int lane = tid & 63;
    const int r    = lane & 15;     // MFMA row/col index
    const int cg   = lane >> 4;     // k-group 0..3
    const int row0 = blockIdx.x * 64 + w * 16;  // flattened (b*2048+n) row of wave
    const int b    = row0 >> 11;
    const int n0   = row0 & 2047;
    const int arow = row0 + r;

    f32x4 acc[8] = {};

#pragma unroll
    for (int k0 = 0; k0 < 128; k0 += 32) {
        // A-fragment: X[arow][k0 + cg*8 + jj]  (f32 -> bf16)
        const float* xp = X + (size_t)arow * 128 + k0 + cg * 8;
        ushort8 xa;
#pragma unroll
        for (int j = 0; j < 8; j++) xa[j] = f2b(xp[j]);
        bf16x8 av = __builtin_bit_cast(bf16x8, xa);
#pragma unroll
        for (int ut = 0; ut < 8; ut++) {
            // B-fragment: W[k][u] = WT[ut*16+r][k0+cg*8 .. +7]  (16B contiguous)
            ushort8 wb = *(const ushort8*)(WT + (size_t)(ut * 16 + r) * 128 + k0 + cg * 8);
            acc[ut] = __builtin_amdgcn_mfma_f32_16x16x32_bf16(
                av, __builtin_bit_cast(bf16x8, wb), acc[ut], 0, 0, 0);
        }
    }

    // D layout: lane holds H[row0 + cg*4 + reg][ut*16 + r]
    float sp[4] = {0.f, 0.f, 0.f, 0.f};
    float tp[4] = {0.f, 0.f, 0.f, 0.f};
#pragma unroll
    for (int ut = 0; ut < 8; ut++) {
        int u = ut * 16 + r;
        float as = a[u];
        float ad = a[128 + u];
#pragma unroll
        for (int reg = 0; reg < 4; reg++) {
            float h = acc[ut][reg];
            int nrow = n0 + cg * 4 + reg;
            HT[((size_t)b * 128 + u) * 2048 + nrow] = f2b(h);
            sp[reg] += h * as;
            tp[reg] += h * ad;
        }
    }
    // reduce partial dot-products across the 16 column-lanes (bits 0..3)
#pragma unroll
    for (int msk = 1; msk < 16; msk <<= 1) {
#pragma unroll
        for (int reg = 0; reg < 4; reg++) {
            sp[reg] += __shfl_xor(sp[reg], msk);
            tp[reg] += __shfl_xor(tp[reg], msk);
        }
    }
    if (r == 0) {
#pragma unroll
        for (int reg = 0; reg < 4; reg++) {
            int row = row0 + cg * 4 + reg;
            sbuf[row] = sp[reg];
            tbuf[row] = tp[reg];
        }
    }
}

// ---------------- K2: fused masked-softmax attention @ H ----------------
// grid = (N/16, B); block = 256 (4 waves).
// Block computes 16 i-rows x 128 u. Wave w owns j in [w*512, w*512+512),
// online softmax per wave, LDS combine at the end.
__global__ __launch_bounds__(256, 4) void k_attn(const int* __restrict__ A,
                                                 const unsigned short* __restrict__ HT,
                                                 const float* __restrict__ sbuf,
                                                 const float* __restrict__ tbuf,
                                                 float* __restrict__ out) {
    const int tid  = threadIdx.x;
    const int w    = tid >> 6;
    const int lane = tid & 63;
    const int r    = lane & 15;
    const int cg   = lane >> 4;
    const int b    = blockIdx.y;
    const int i0   = blockIdx.x * 16;            // batch-local i base of block
    const int srow = i0 + r;                     // P row owned by this lane

    const float s_r = sbuf[b * 2048 + srow];
    const int* Arow   = A + ((size_t)b * 2048 + srow) * 2048 + w * 512;
    const float* trow = tbuf + (size_t)b * 2048 + w * 512;
    const unsigned short* Hb = HT + (size_t)b * 128 * 2048;

    f32x4 acc[8] = {};
    float m = NEG_INF;
    float den = 0.f;

    // prefetch tile 0
    int4 a0 = *(const int4*)(Arow + cg * 8);
    int4 a1 = *(const int4*)(Arow + cg * 8 + 4);
    float4 t0 = *(const float4*)(trow + cg * 8);
    float4 t1 = *(const float4*)(trow + cg * 8 + 4);

    for (int jt = 0; jt < 16; ++jt) {
        int   ai[8] = {a0.x, a0.y, a0.z, a0.w, a1.x, a1.y, a1.z, a1.w};
        float tv[8] = {t0.x, t0.y, t0.z, t0.w, t1.x, t1.y, t1.z, t1.w};
        if (jt < 15) {   // prefetch next tile
            int off = (jt + 1) * 32 + cg * 8;
            a0 = *(const int4*)(Arow + off);
            a1 = *(const int4*)(Arow + off + 4);
            t0 = *(const float4*)(trow + off);
            t1 = *(const float4*)(trow + off + 4);
        }

        float ev[8];
        float mloc = NEG_INF;
#pragma unroll
        for (int jj = 0; jj < 8; jj++) {
            float x = s_r + tv[jj];
            float e = x > 0.f ? x : 0.2f * x;        // leaky_relu
            e = ai[jj] > 0 ? e : NEG_INF;            // mask
            ev[jj] = e;
            mloc = fmaxf(mloc, e);
        }
        // row max across the 4 k-groups holding this row
        mloc = fmaxf(mloc, __shfl_xor(mloc, 16));
        mloc = fmaxf(mloc, __shfl_xor(mloc, 32));
        float mn  = fmaxf(m, mloc);
        float fac = __expf(m - mn);

        float psum = 0.f;
        ushort8 pb;
#pragma unroll
        for (int jj = 0; jj < 8; jj++) {
            float p = ai[jj] > 0 ? __expf(ev[jj] - mn) : 0.f;
            psum += p;
            pb[jj] = f2b(p);
        }
        den = den * fac + psum;
        m = mn;

        // rescale accumulators (acc rows are cg*4+reg; fetch their factors)
        if (__any(fac < 1.f)) {
            float f0 = __shfl(fac, cg * 4 + 0);
            float f1 = __shfl(fac, cg * 4 + 1);
            float f2 = __shfl(fac, cg * 4 + 2);
            float f3 = __shfl(fac, cg * 4 + 3);
#pragma unroll
            for (int ut = 0; ut < 8; ut++) {
                acc[ut][0] *= f0;
                acc[ut][1] *= f1;
                acc[ut][2] *= f2;
                acc[ut][3] *= f3;
            }
        }

        const int jb = w * 512 + jt * 32 + cg * 8;
        bf16x8 pa = __builtin_bit_cast(bf16x8, pb);
#pragma unroll
        for (int ut = 0; ut < 8; ut++) {
            // B-fragment: H[j][u] = HT[ut*16+r][jb .. jb+7] (16B contiguous)
            ushort8 hb = *(const ushort8*)(Hb + (size_t)(ut * 16 + r) * 2048 + jb);
            acc[ut] = __builtin_amdgcn_mfma_f32_16x16x32_bf16(
                pa, __builtin_bit_cast(bf16x8, hb), acc[ut], 0, 0, 0);
        }
    }

    // per-wave denominator per row: sum the 4 k-group partials (same m)
    den += __shfl_xor(den, 16);
    den += __shfl_xor(den, 32);

    // ---- cross-wave combine via LDS ----
    __shared__ float accS[4][16][128];   // 32 KB
    __shared__ float mS[4][16];
    __shared__ float dS[4][16];

    if (cg == 0) { mS[w][r] = m; dS[w][r] = den; }
#pragma unroll
    for (int ut = 0; ut < 8; ut++)
#pragma unroll
        for (int reg = 0; reg < 4; reg++)
            accS[w][cg * 4 + reg][ut * 16 + r] = acc[ut][reg];
    __syncthreads();

    const int row = tid >> 4;          // 0..15
    const int ub  = (tid & 15) * 8;    // 0..120
    float m0 = mS[0][row], m1 = mS[1][row], m2 = mS[2][row], m3 = mS[3][row];
    float M  = fmaxf(fmaxf(m0, m1), fmaxf(m2, m3));
    float f0 = __expf(m0 - M), f1 = __expf(m1 - M);
    float f2 = __expf(m2 - M), f3 = __expf(m3 - M);
    float denom = dS[0][row] * f0 + dS[1][row] * f1 + dS[2][row] * f2 + dS[3][row] * f3;
    float inv = 1.0f / denom;

    float o[8];
#pragma unroll
    for (int k = 0; k < 8; k++) {
        float num = accS[0][row][ub + k] * f0 + accS[1][row][ub + k] * f1
                  + accS[2][row][ub + k] * f2 + accS[3][row][ub + k] * f3;
        o[k] = fmaxf(num * inv, 0.f);
    }
    float* op = out + ((size_t)b * 2048 + i0 + row) * 128 + ub;
    *(float4*)(op)     = make_float4(o[0], o[1], o[2], o[3]);
    *(float4*)(op + 4) = make_float4(o[4], o[5], o[6], o[7]);
}

extern "C" void kernel_launch(void* const* d_in, const int* in_sizes, int n_in,
                              void* d_out, int out_size, void* d_ws, size_t ws_size,
                              hipStream_t stream) {
    const float* X = (const float*)d_in[0];   // (8,2048,128) f32
    const int*   A = (const int*)d_in[1];     // (8,2048,2048) i32
    const float* W = (const float*)d_in[2];   // (128,128) f32
    const float* a = (const float*)d_in[3];   // (256,1) f32
    float* out = (float*)d_out;               // (8,2048,128) f32

    char* ws = (char*)d_ws;
    unsigned short* WT  = (unsigned short*)(ws);                  // 32 KB
    float*          sb  = (float*)(ws + 32768);                   // 64 KB
    float*          tb  = (float*)(ws + 32768 + 65536);           // 64 KB
    unsigned short* HT  = (unsigned short*)(ws + 32768 + 131072); // 4 MB

    k_wt<<<dim3(64), dim3(256), 0, stream>>>(W, WT);
    k_h<<<dim3(256), dim3(256), 0, stream>>>(X, WT, a, HT, sb, tb);
    k_attn<<<dim3(128, 8), dim3(256), 0, stream>>>(A, HT, sb, tb, out);
}